// Round 7
// baseline (317.213 us; speedup 1.0000x reference)
//
#include <hip/hip_runtime.h>
#include <hip/hip_bf16.h>
#include <stdint.h>

// ---------------------------------------------------------------------------
// EfficientCrossAttention on MI355X (gfx950), bf16 MFMA pipeline.
// prep (cast+transpose) -> fused Q/KV projection GEMM -> flash attention
// (S^T trick; 32q x 32key per wave, all full-rate K=32 MFMA) -> Oproj GEMM.
// History: R8 full-rate PV (104.7->84.8us); R10 Vt key-permute (->80.8us,
// conflicts 9.2M->0.79M); R11 PV-deferral REGRESSED; R12 V-from-global with
// 4KB/lane stride REGRESSED (transaction-bound); R13 Vfrag coalesced layout
// (82.8us, VALUBusy -7, FETCH -23%) — NEUTRAL on duration: LDS demand was
// not the gate. R13 counters: MfmaUtil 42.4 + VALUBusy 43.6 = 86%, runtime
// = MFMA-cy + VALU-cy SERIAL. The per-tile __syncthreads (only needed for
// the block-shared K dbuf) phase-locks all waves -> zero cross-wave pipe
// overlap.
// R14: BARRIER-FREE main loop. Per-wave private K ring (each wave stages
// its own 32 keys, 2x4KB LDS slice via global_load_lds) -> no cross-wave
// hazard -> no in-loop barrier -> waves drift, one wave's exp overlaps
// another's MFMA (m114). Wave-local sync via asm s_waitcnt vmcnt(0) at
// tile top (K(t) issued a full tile earlier; in-order retirement makes
// the count exact; memory clobber orders the following ds_read).
// Cost: K staged twice per block (wq dup) -> L2 K+V ~25TB/s < 34.5 ceiling.
// Pool 8KB sQ + 4x8KB rings = 40960B -> exactly 4 blocks/CU.
// d_ws layout:
//   WqT @0MB  WkvT @2MB  WoT @6MB  qb @8MB  kvb @24MB
//   Qp (B*H,2048,64) @40MB   Kb (B*H,2048,64) @56MB
//   Vfrag (16MB) @72MB       Ob (8192x1024)   @88MB
// ---------------------------------------------------------------------------

typedef __bf16 bf16_t;
typedef __bf16 bf16x8 __attribute__((ext_vector_type(8)));
typedef __bf16 bf16x4 __attribute__((ext_vector_type(4)));
typedef short  s16x4  __attribute__((ext_vector_type(4)));
typedef float  f32x4  __attribute__((ext_vector_type(4)));

#define MFMA16x32(a, b, c) __builtin_amdgcn_mfma_f32_16x16x32_bf16((a), (b), (c), 0, 0, 0)

__device__ __forceinline__ float fast_exp2(float x) {
#if __has_builtin(__builtin_amdgcn_exp2f)
    return __builtin_amdgcn_exp2f(x);
#else
    return exp2f(x);
#endif
}

// async global->LDS, 16B/lane; LDS dest = wave-uniform base + lane*16
__device__ __forceinline__ void gload16(const void* g, const void* l) {
    __builtin_amdgcn_global_load_lds(
        (__attribute__((address_space(1))) void*)(uintptr_t)g,
        (__attribute__((address_space(3))) void*)(uintptr_t)l,
        16, 0, 0);
}

// log2(e)/sqrt(HD=64), folded into the Q projection epilogue
#define ATTN_SCALE 0.18033688011112042f

// ---------------------------------------------------------------------------
// merged prep: fp32->bf16 casts (blocks 0..8191) + 3 weight transposes
__global__ void prep_kernel(const float* __restrict__ q, const float* __restrict__ kv,
                            const float* __restrict__ Wq, const float* __restrict__ Wkv,
                            const float* __restrict__ Wo, bf16_t* __restrict__ qb,
                            bf16_t* __restrict__ kvb, bf16_t* __restrict__ WqT,
                            bf16_t* __restrict__ WkvT, bf16_t* __restrict__ WoT) {
    __shared__ float tile[64][65];
    int bid = blockIdx.x;
    const int t = threadIdx.x;
    if (bid < 8192) {
        const float* in;
        bf16_t* out;
        if (bid < 4096) { in = q; out = qb; }
        else            { in = kv; out = kvb; bid -= 4096; }
        int i = (bid * 256 + t) * 8;
        const float4* p = (const float4*)(in + i);
        float4 x = p[0], y = p[1];
        bf16x8 v;
        v[0] = (bf16_t)x.x; v[1] = (bf16_t)x.y; v[2] = (bf16_t)x.z; v[3] = (bf16_t)x.w;
        v[4] = (bf16_t)y.x; v[5] = (bf16_t)y.y; v[6] = (bf16_t)y.z; v[7] = (bf16_t)y.w;
        *(bf16x8*)(out + i) = v;
        return;
    }
    bid -= 8192;
    int z = bid >> 9, rem = bid & 511;
    int xb = rem & 31, yb = rem >> 5;
    const float* W;
    bf16_t* WT;
    int N;
    if (z == 0)      { W = Wq;  WT = WqT;  N = 1024; }
    else if (z == 1) { W = Wkv; WT = WkvT; N = 2048; }
    else             { W = Wo;  WT = WoT;  N = 1024; }
    if (xb * 64 >= N) return;
    const int K = 1024;
    const int n0 = xb * 64, k0 = yb * 64;
#pragma unroll
    for (int i = 0; i < 16; ++i) {
        int idx = i * 256 + t;
        int r = idx >> 6, c = idx & 63;
        tile[r][c] = W[(size_t)(k0 + r) * N + n0 + c];
    }
    __syncthreads();
#pragma unroll
    for (int i = 0; i < 16; ++i) {
        int idx = i * 256 + t;
        int r = idx >> 6, c = idx & 63;
        WT[(size_t)(n0 + r) * K + k0 + c] = (bf16_t)tile[c][r];
    }
}

// ---------------------------------------------------------------------------
// Fused Q + KV projection GEMM (one launch, 24x64 = 1536 blocks).
// blockIdx.x < 8: Qproj (scaled, -> Qp); else KVproj (-> Kb / Vfrag).
// 128x128 tiles, m97 staging, 2-bit XOR chunk swizzle.
// V epilogue writes attn-fragment order directly from accumulators:
// Vfrag element offset = (((bh*32+t)*2+wk)*4+nh)*512 + lane*8 + e, where
// e<4 -> key wk*32+quad*4+e (acc[2wk][n]), e>=4 -> key wk*32+16+quad*4+(e-4)
// (acc[2wk+1][n]). Each (wk,nh) block is 1KB, lane-contiguous.
__global__ __launch_bounds__(256, 3)
void gemm_qkv(const bf16_t* __restrict__ qb, const bf16_t* __restrict__ kvb,
              const bf16_t* __restrict__ WqT, const bf16_t* __restrict__ WkvT,
              const float* __restrict__ bq, const float* __restrict__ bkv,
              bf16_t* __restrict__ Qp, bf16_t* __restrict__ Kb,
              bf16_t* __restrict__ Vt) {
    __shared__ __align__(16) char pool[16384];
    bf16_t* sA = (bf16_t*)pool;
    bf16_t* sB = (bf16_t*)(pool + 8192);

    const int tid  = threadIdx.x;
    const int lane = tid & 63, w = tid >> 6;
    const int wr = w >> 1, wc = w & 1;
    const int quad = lane >> 4, l15 = lane & 15;
    const int x3 = l15 & 3;
    const bool isQ = blockIdx.x < 8;
    const bf16_t* A    = isQ ? qb : kvb;
    const bf16_t* BT   = isQ ? WqT : WkvT;
    const float*  bias = isQ ? bq : bkv;
    const int row0 = blockIdx.y * 128;
    const int col0 = (isQ ? blockIdx.x : (blockIdx.x - 8)) * 128;
    const int K = 1024;

    f32x4 acc[4][4];
    const f32x4 fz = {0.f, 0.f, 0.f, 0.f};
#pragma unroll
    for (int m = 0; m < 4; ++m)
#pragma unroll
        for (int n = 0; n < 4; ++n) acc[m][n] = fz;

    for (int kt = 0; kt < K; kt += 32) {
#pragma unroll
        for (int i = 0; i < 2; ++i) {
            int c = i * 256 + tid;
            int r = c >> 2, cr = c & 3;
            int g = cr ^ (r & 3);
            gload16(A + (size_t)(row0 + r) * K + kt + g * 8,
                    (const char*)sA + i * 4096 + w * 1024);
            gload16(BT + (size_t)(col0 + r) * K + kt + g * 8,
                    (const char*)sB + i * 4096 + w * 1024);
        }
        __syncthreads();

        bf16x8 af[4], bfr[4];
#pragma unroll
        for (int m = 0; m < 4; ++m)
            af[m] = *(const bf16x8*)(sA + (wr * 64 + m * 16 + l15) * 32 + (quad ^ x3) * 8);
#pragma unroll
        for (int n = 0; n < 4; ++n)
            bfr[n] = *(const bf16x8*)(sB + (wc * 64 + n * 16 + l15) * 32 + (quad ^ x3) * 8);
#pragma unroll
        for (int m = 0; m < 4; ++m)
#pragma unroll
            for (int n = 0; n < 4; ++n)
                acc[m][n] = MFMA16x32(af[m], bfr[n], acc[m][n]);
        __syncthreads();
    }

    if (!isQ && col0 >= 1024) {
        // pure-V block: write Vfrag directly from accumulators (coalesced
        // 16B/lane stores, 1KB per (wk,nh) block). No LDS transpose.
        const int j0  = col0 - 1024 + wc * 64;   // V column base = head h*64
        const int hh  = j0 >> 6;                 // head index
        const int sk0 = row0 + wr * 64;          // key base (one 64-key tile)
        const int bb  = sk0 >> 11;               // batch
        const int tt  = (sk0 & 2047) >> 6;       // key tile within batch-head
        bf16_t* vdst = Vt + ((((size_t)(bb * 16 + hh) * 32 + tt) * 2) * 4) * 512 +
                       (size_t)lane * 8;
#pragma unroll
        for (int wkh = 0; wkh < 2; ++wkh)
#pragma unroll
            for (int n = 0; n < 4; ++n) {
                float bv = bkv[1024 + j0 + n * 16 + l15];
                bf16x8 v8;
#pragma unroll
                for (int r = 0; r < 4; ++r) {
                    v8[r]     = (bf16_t)(acc[2 * wkh][n][r] + bv);
                    v8[4 + r] = (bf16_t)(acc[2 * wkh + 1][n][r] + bv);
                }
                *(bf16x8*)(vdst + ((size_t)wkh * 4 + n) * 512) = v8;
            }
        return;
    }

#pragma unroll
    for (int m = 0; m < 4; ++m) {
        int rg_base = row0 + wr * 64 + m * 16 + quad * 4;
#pragma unroll
        for (int n = 0; n < 4; ++n) {
            int cg = col0 + wc * 64 + n * 16 + l15;
            float bv = bias[cg];
#pragma unroll
            for (int r = 0; r < 4; ++r) {
                int rg = rg_base + r;
                float v = acc[m][n][r] + bv;
                int bb = rg >> 11, sr = rg & 2047;
                int hh = cg >> 6, hd = cg & 63;
                size_t idx = (((size_t)(bb * 16 + hh) * 2048 + sr) << 6) | hd;
                if (isQ) Qp[idx] = (bf16_t)(v * ATTN_SCALE);
                else     Kb[idx] = (bf16_t)v;
            }
        }
    }
}

// ---------------------------------------------------------------------------
// Oproj GEMM: C = A(MxK) * BT(NxK)^T + bias, fp32 row-major out.
__global__ __launch_bounds__(256, 3)
void gemm_out(const bf16_t* __restrict__ A, const bf16_t* __restrict__ BT,
              const float* __restrict__ bias, float* __restrict__ out,
              int M, int N, int K) {
    __shared__ __align__(16) bf16_t sA[128 * 32];
    __shared__ __align__(16) bf16_t sB[128 * 32];
    const int tid  = threadIdx.x;
    const int lane = tid & 63, w = tid >> 6;
    const int wr = w >> 1, wc = w & 1;
    const int quad = lane >> 4, l15 = lane & 15;
    const int x3 = l15 & 3;
    const int row0 = blockIdx.y * 128, col0 = blockIdx.x * 128;

    f32x4 acc[4][4];
    const f32x4 fz = {0.f, 0.f, 0.f, 0.f};
#pragma unroll
    for (int m = 0; m < 4; ++m)
#pragma unroll
        for (int n = 0; n < 4; ++n) acc[m][n] = fz;

    for (int kt = 0; kt < K; kt += 32) {
#pragma unroll
        for (int i = 0; i < 2; ++i) {
            int c = i * 256 + tid;
            int r = c >> 2, cr = c & 3;
            int g = cr ^ (r & 3);
            gload16(A + (size_t)(row0 + r) * K + kt + g * 8,
                    (const char*)sA + i * 4096 + w * 1024);
            gload16(BT + (size_t)(col0 + r) * K + kt + g * 8,
                    (const char*)sB + i * 4096 + w * 1024);
        }
        __syncthreads();

        bf16x8 af[4], bfr[4];
#pragma unroll
        for (int m = 0; m < 4; ++m)
            af[m] = *(const bf16x8*)(sA + (wr * 64 + m * 16 + l15) * 32 + (quad ^ x3) * 8);
#pragma unroll
        for (int n = 0; n < 4; ++n)
            bfr[n] = *(const bf16x8*)(sB + (wc * 64 + n * 16 + l15) * 32 + (quad ^ x3) * 8);
#pragma unroll
        for (int m = 0; m < 4; ++m)
#pragma unroll
            for (int n = 0; n < 4; ++n)
                acc[m][n] = MFMA16x32(af[m], bfr[n], acc[m][n]);
        __syncthreads();
    }

#pragma unroll
    for (int m = 0; m < 4; ++m) {
        int rg_base = row0 + wr * 64 + m * 16 + quad * 4;
#pragma unroll
        for (int n = 0; n < 4; ++n) {
            int cg = col0 + wc * 64 + n * 16 + l15;
            float bv = bias[cg];
#pragma unroll
            for (int r = 0; r < 4; ++r)
                out[(size_t)(rg_base + r) * N + cg] = acc[m][n][r] + bv;
        }
    }
}

// ---------------------------------------------------------------------------
// Flash attention. 1-D grid of 2048 blocks, bh-major: bh = id&63, qt = id>>6.
// Wave w = (wq = w>>1 q-half, wk = w&1 key-half): 32 q-rows x 32 keys per
// wave, all MFMAs full-rate 16x16x32. In-tile order: QK -> exp -> PV.
// R14: BARRIER-FREE loop. Each wave owns a private K ring (2 x 4KB at
// pool + 8192 + w*8192) and stages only ITS 32 keys via gload16 (4 x 1KB,
// lane map: row_local = j*8 + (lane>>3), slot = lane&7 holds global chunk
// (lane&7)^(lane>>3) -> same c^(r&7) swizzle identity as before, so kf
// reads keep the (quad^x7) addressing). V from global Vfrag (R13).
// No cross-wave LDS hazard -> no in-loop __syncthreads -> waves drift ->
// one wave's exp overlaps another's MFMA (m114). Wave-local ordering: asm
// s_waitcnt vmcnt(0) (+memory clobber) at tile top; K(t) was issued a full
// tile (~6k cy) earlier so the wait is free; in-order vmcnt retirement
// makes the count exact (only K(t)'s 4 stages outstanding there).
// Pool 40960B: sQ@0 (8KB, persistent), rings@8192 (4x8KB) -> 4 blocks/CU.
// Epilogue: one barrier to drain all waves (rings overlay redO/redL),
// then redL write, then the 2-phase redO reduction as before.
// __launch_bounds__(256,4); spill tripwire: WRITE_SIZE ~16.5k.
__global__ __launch_bounds__(256, 4)
void attn_kernel(const bf16_t* __restrict__ Qp, const bf16_t* __restrict__ Kb,
                 const bf16_t* __restrict__ Vt, bf16_t* __restrict__ Ob) {
    __shared__ __align__(16) char pool[40960];
    bf16_t* sQ   = (bf16_t*)pool;
    float*  redO = (float*)pool;               // [4][32][32] (end phase)
    float*  redL = (float*)(pool + 16384);     // [4][32]   (end phase)

    const int tid = threadIdx.x;
    const int lane = tid & 63, w = tid >> 6;
    const int wq = w >> 1, wk = w & 1;
    const int quad = lane >> 4, l15 = lane & 15;
    const int x7 = l15 & 7;
    const int bhid = blockIdx.x & 63;
    const int qt   = blockIdx.x >> 6;
    const int b = bhid >> 4, h = bhid & 15;
    const size_t bh = (size_t)bhid;

    const bf16_t* Qg = Qp + bh * (2048 * 64) + (size_t)qt * (64 * 64);
    const bf16_t* Kg = Kb + bh * (2048 * 64);
    // Vfrag: element = bh*131072 + t*4096 + wk*2048 + nh*512 + lane*8 + e
    const bf16_t* vtile = Vt + bh * 131072 + (size_t)wk * 2048 + (size_t)lane * 8;

    // Q staging map (block-cooperative, as before)
    const int srow = tid >> 3;
    const int sg   = (tid & 7) ^ (srow & 7);

    // K private-ring staging map: wave stages rows wk*32 + j*8 + (lane>>3),
    // slot lane&7 <- global chunk (lane&7)^(lane>>3)
    const bf16_t* Kw = Kg + wk * 2048;           // our 32-key half, tile 0
    const int krl = lane >> 3;
    const size_t klo = (size_t)krl * 64 + (size_t)(((lane & 7) ^ krl)) * 8;
    char* kring = pool + 8192 + w * 8192;

    // stage Q (cooperative) + K(0) (private)
#pragma unroll
    for (int hh = 0; hh < 2; ++hh) {
        int row = hh * 32 + srow;
        gload16(Qg + (size_t)row * 64 + sg * 8, pool + hh * 4096 + w * 1024);
    }
#pragma unroll
    for (int j = 0; j < 4; ++j)
        gload16(Kw + (size_t)j * 512 + klo, kring + j * 1024);
    __syncthreads();   // sQ fully staged (also drains our K(0) gload16s)

    // Q B-frags: our 32 q-rows, both hd halves (sQ persists all loop)
    bf16x8 qf[2][2];
#pragma unroll
    for (int qb = 0; qb < 2; ++qb)
#pragma unroll
        for (int hh = 0; hh < 2; ++hh)
            qf[qb][hh] = *(const bf16x8*)(sQ + (wq * 32 + qb * 16 + l15) * 64 +
                                          ((hh * 4 + quad) ^ x7) * 8);

    const f32x4 fz = {0.f, 0.f, 0.f, 0.f};
    bf16x8 ones8;
#pragma unroll
    for (int i = 0; i < 8; ++i) ones8[i] = (bf16_t)1.f;

    f32x4 o_[2][4];   // [qb][nh]: O[wq*32+qb*16+quad*4+r][nh*16+l15], partial over our keys
    f32x4 lacc[2];    // [qb]: row-sum partials
#pragma unroll
    for (int qb = 0; qb < 2; ++qb) {
        lacc[qb] = fz;
#pragma unroll
        for (int nh = 0; nh < 4; ++nh) o_[qb][nh] = fz;
    }

    for (int t = 0; t < 32; ++t) {
        // K(t) ring ready: only its 4 stages can be outstanding here
        asm volatile("s_waitcnt vmcnt(0)" ::: "memory");

        const bf16_t* k0 = (const bf16_t*)(kring + ((t & 1) << 12));
        bf16x8 kf0[2], kf1[2];
#pragma unroll
        for (int kg = 0; kg < 2; ++kg) {
            const bf16_t* krow = k0 + (kg * 16 + l15) * 64;
            kf0[kg] = *(const bf16x8*)(krow + (quad ^ x7) * 8);
            kf1[kg] = *(const bf16x8*)(krow + ((quad + 4) ^ x7) * 8);
        }

        // stage K(t+1) into the other ring half (private, no barrier)
        if (t < 31) {
            const bf16_t* Kt = Kw + (size_t)(t + 1) * 4096;
            char* kb_ = kring + (((t + 1) & 1) << 12);
#pragma unroll
            for (int j = 0; j < 4; ++j)
                gload16(Kt + (size_t)j * 512 + klo, kb_ + j * 1024);
        }

        // V(t): coalesced 16B/lane global loads (first use at PV below)
        bf16x8 vf[4];
#pragma unroll
        for (int nh = 0; nh < 4; ++nh)
            vf[nh] = *(const bf16x8*)(vtile + (size_t)t * 4096 + nh * 512);

        // QK: S^T[key=wk*32+kg*16+quad*4+r][qrow=wq*32+qb*16+l15]
        f32x4 s_[2][2];
#pragma unroll
        for (int kg = 0; kg < 2; ++kg)
#pragma unroll
            for (int qb = 0; qb < 2; ++qb) {
                s_[kg][qb] = MFMA16x32(kf0[kg], qf[qb][0], fz);
                s_[kg][qb] = MFMA16x32(kf1[kg], qf[qb][1], s_[kg][qb]);
            }

        // p = exp2(s), packed K=32 A-frags (e<4: kg0, e>=4: kg1);
        // row sums via K=32 MFMA against ones
        bf16x8 pf8[2];
#pragma unroll
        for (int qb = 0; qb < 2; ++qb) {
#pragma unroll
            for (int kg = 0; kg < 2; ++kg)
#pragma unroll
                for (int r = 0; r < 4; ++r)
                    pf8[qb][kg * 4 + r] = (bf16_t)fast_exp2(s_[kg][qb][r]);
            lacc[qb] = MFMA16x32(pf8[qb], ones8, lacc[qb]);
        }

        // PV: vf virtual k-order matches pf8 (Vfrag layout)
#pragma unroll
        for (int nh = 0; nh < 4; ++nh)
#pragma unroll
            for (int qb = 0; qb < 2; ++qb)
                o_[qb][nh] = MFMA16x32(pf8[qb], vf[nh], o_[qb][nh]);
        // no __syncthreads: waves drift freely
    }

    // ---- epilogue: drain all waves, then 2-way cross-wave (wk) reduction ----
    __syncthreads();   // all waves done with their K rings (redO/redL overlay)

    if (l15 == 0) {
#pragma unroll
        for (int qb = 0; qb < 2; ++qb)
#pragma unroll
            for (int r = 0; r < 4; ++r)
                redL[w * 32 + qb * 16 + quad * 4 + r] = lacc[qb][r];
    }

    const int cq  = tid >> 2;           // consumer q-row 0..63
    const int cwq = cq >> 5, cql = cq & 31;
    const int chb = (tid & 3) * 8;      // consumer hd base within 32-phase
    const size_t orow = (size_t)b * 2048 + (size_t)qt * 64 + cq;

#pragma unroll
    for (int ph = 0; ph < 2; ++ph) {
        __syncthreads();  // prior phase consumed; redL visible (ph=0)
#pragma unroll
        for (int qb = 0; qb < 2; ++qb)
#pragma unroll
            for (int nj = 0; nj < 2; ++nj) {
                int nh = ph * 2 + nj;
#pragma unroll
                for (int r = 0; r < 4; ++r)
                    redO[w * 1024 + (qb * 16 + quad * 4 + r) * 32 + nj * 16 + l15] =
                        o_[qb][nh][r];
            }
        __syncthreads();  // partials visible

        float lt = redL[cwq * 64 + cql] + redL[cwq * 64 + 32 + cql];
        float linv = 1.f / lt;
        float4 a0 = {0, 0, 0, 0}, a1 = {0, 0, 0, 0};
#pragma unroll
        for (int wk2 = 0; wk2 < 2; ++wk2) {
            const float4* p = (const float4*)(redO + (cwq * 2 + wk2) * 1024 + cql * 32 + chb);
            float4 x = p[0], y = p[1];
            a0.x += x.x; a0.y += x.y; a0.z += x.z; a0.w += x.w;
            a1.x += y.x; a1.y += y.y; a1.z += y.z; a1.w += y.w;
        }
        bf16x8 ov;
        ov[0] = (bf16_t)(a0.x * linv); ov[1] = (bf16_t)(a0.y * linv);
        ov[2] = (bf16_t)(a0.z * linv); ov[3] = (bf16_t)(a0.w * linv);
        ov[4] = (bf16_t)(a1.x * linv); ov[5] = (bf16_t)(a1.y * linv);
        ov[6] = (bf16_t)(a1.z * linv); ov[7] = (bf16_t)(a1.w * linv);
        *(bf16x8*)(Ob + orow * 1024 + h * 64 + ph * 32 + chb) = ov;
    }
}

// ---------------------------------------------------------------------------
extern "C" void kernel_launch(void* const* d_in, const int* in_sizes, int n_in,
                              void* d_out, int out_size, void* d_ws, size_t ws_size,
                              hipStream_t stream) {
    const float* query     = (const float*)d_in[0];
    const float* key_value = (const float*)d_in[1];
    const float* Wq  = (const float*)d_in[2];
    const float* bq  = (const float*)d_in[3];
    const float* Wkv = (const float*)d_in[4];
    const float* bkv = (const float*)d_in[5];
    const float* Wo  = (const float*)d_in[6];
    const float* bo  = (const float*)d_in[7];
    float* out = (float*)d_out;

    char* ws = (char*)d_ws;
    const size_t MB = 1024 * 1024;
    bf16_t* WqT  = (bf16_t*)(ws + 0 * MB);
    bf16_t* WkvT = (bf16_t*)(ws + 2 * MB);
    bf16_t* WoT  = (bf16_t*)(ws + 6 * MB);
    bf16_t* qb   = (bf16_t*)(ws + 8 * MB);
    bf16_t* kvb  = (bf16_t*)(ws + 24 * MB);
    bf16_t* Qp   = (bf16_t*)(ws + 40 * MB);
    bf16_t* Kb   = (bf16_t*)(ws + 56 * MB);
    bf16_t* Vt   = (bf16_t*)(ws + 72 * MB);
    bf16_t* Ob   = (bf16_t*)(ws + 88 * MB);

    prep_kernel<<<9728, 256, 0, stream>>>(query, key_value, Wq, Wkv, Wo,
                                          qb, kvb, WqT, WkvT, WoT);
    gemm_qkv<<<dim3(24, 64), 256, 0, stream>>>(qb, kvb, WqT, WkvT, bq, bkv,
                                               Qp, Kb, Vt);
    attn_kernel<<<2048, 256, 0, stream>>>(Qp, Kb, Vt, Ob);
    gemm_out<<<dim3(8, 64), 256, 0, stream>>>(Ob, WoT, bo, out, 8192, 1024, 1024);
}

// Round 9
// 312.674 us; speedup vs baseline: 1.0145x; 1.0145x over previous
//
#include <hip/hip_runtime.h>
#include <hip/hip_bf16.h>
#include <stdint.h>

// ---------------------------------------------------------------------------
// EfficientCrossAttention on MI355X (gfx950), bf16 MFMA pipeline.
// prep (cast+transpose) -> fused Q/KV projection GEMM -> flash attention
// (S^T trick; 32q x 32key per wave, all full-rate K=32 MFMA) -> Oproj GEMM.
// History: R8 full-rate PV (104.7->84.8us); R10 Vt key-permute (->80.8us);
// R11 PV-deferral REGRESSED; R12 V-from-global 4KB-stride REGRESSED;
// R13 Vfrag coalesced (82.8us, NEUTRAL); R14 barrier-free private K rings
// REGRESSED (86.6us, MfmaUtil 38.6).
// R15 diagnosis of R13/R14: vmcnt retires IN-ORDER. K(t+1) gload16 stages
// were issued BEFORE the vf register loads, so the compiler's wait for vf
// at PV must drain the K stages too (issued only ~300cy earlier) -> K
// prefetch latency on the critical path at every PV. R13's LDS savings were
// offset by this; R14 exposed it fully (no barrier to amortize).
// R15 fix: issue vf loads FIRST, then K(t+1) stages. PV's wait becomes
// vmcnt(4) (K stays in flight); tile-top vmcnt(0) waits K issued a full
// tile (~5k cy) earlier. sched_barrier(0) pins the issue order. Barrier-
// free structure retained (waves drift; exp overlaps MFMA across waves).
// R16: unchanged resubmit — R15 bench hit GPUAcquisitionTimeout (no data).
// d_ws layout:
//   WqT @0MB  WkvT @2MB  WoT @6MB  qb @8MB  kvb @24MB
//   Qp (B*H,2048,64) @40MB   Kb (B*H,2048,64) @56MB
//   Vfrag (16MB) @72MB       Ob (8192x1024)   @88MB
// ---------------------------------------------------------------------------

typedef __bf16 bf16_t;
typedef __bf16 bf16x8 __attribute__((ext_vector_type(8)));
typedef __bf16 bf16x4 __attribute__((ext_vector_type(4)));
typedef short  s16x4  __attribute__((ext_vector_type(4)));
typedef float  f32x4  __attribute__((ext_vector_type(4)));

#define MFMA16x32(a, b, c) __builtin_amdgcn_mfma_f32_16x16x32_bf16((a), (b), (c), 0, 0, 0)

__device__ __forceinline__ float fast_exp2(float x) {
#if __has_builtin(__builtin_amdgcn_exp2f)
    return __builtin_amdgcn_exp2f(x);
#else
    return exp2f(x);
#endif
}

// async global->LDS, 16B/lane; LDS dest = wave-uniform base + lane*16
__device__ __forceinline__ void gload16(const void* g, const void* l) {
    __builtin_amdgcn_global_load_lds(
        (__attribute__((address_space(1))) void*)(uintptr_t)g,
        (__attribute__((address_space(3))) void*)(uintptr_t)l,
        16, 0, 0);
}

// log2(e)/sqrt(HD=64), folded into the Q projection epilogue
#define ATTN_SCALE 0.18033688011112042f

// ---------------------------------------------------------------------------
// merged prep: fp32->bf16 casts (blocks 0..8191) + 3 weight transposes
__global__ void prep_kernel(const float* __restrict__ q, const float* __restrict__ kv,
                            const float* __restrict__ Wq, const float* __restrict__ Wkv,
                            const float* __restrict__ Wo, bf16_t* __restrict__ qb,
                            bf16_t* __restrict__ kvb, bf16_t* __restrict__ WqT,
                            bf16_t* __restrict__ WkvT, bf16_t* __restrict__ WoT) {
    __shared__ float tile[64][65];
    int bid = blockIdx.x;
    const int t = threadIdx.x;
    if (bid < 8192) {
        const float* in;
        bf16_t* out;
        if (bid < 4096) { in = q; out = qb; }
        else            { in = kv; out = kvb; bid -= 4096; }
        int i = (bid * 256 + t) * 8;
        const float4* p = (const float4*)(in + i);
        float4 x = p[0], y = p[1];
        bf16x8 v;
        v[0] = (bf16_t)x.x; v[1] = (bf16_t)x.y; v[2] = (bf16_t)x.z; v[3] = (bf16_t)x.w;
        v[4] = (bf16_t)y.x; v[5] = (bf16_t)y.y; v[6] = (bf16_t)y.z; v[7] = (bf16_t)y.w;
        *(bf16x8*)(out + i) = v;
        return;
    }
    bid -= 8192;
    int z = bid >> 9, rem = bid & 511;
    int xb = rem & 31, yb = rem >> 5;
    const float* W;
    bf16_t* WT;
    int N;
    if (z == 0)      { W = Wq;  WT = WqT;  N = 1024; }
    else if (z == 1) { W = Wkv; WT = WkvT; N = 2048; }
    else             { W = Wo;  WT = WoT;  N = 1024; }
    if (xb * 64 >= N) return;
    const int K = 1024;
    const int n0 = xb * 64, k0 = yb * 64;
#pragma unroll
    for (int i = 0; i < 16; ++i) {
        int idx = i * 256 + t;
        int r = idx >> 6, c = idx & 63;
        tile[r][c] = W[(size_t)(k0 + r) * N + n0 + c];
    }
    __syncthreads();
#pragma unroll
    for (int i = 0; i < 16; ++i) {
        int idx = i * 256 + t;
        int r = idx >> 6, c = idx & 63;
        WT[(size_t)(n0 + r) * K + k0 + c] = (bf16_t)tile[c][r];
    }
}

// ---------------------------------------------------------------------------
// Fused Q + KV projection GEMM (one launch, 24x64 = 1536 blocks).
// blockIdx.x < 8: Qproj (scaled, -> Qp); else KVproj (-> Kb / Vfrag).
// 128x128 tiles, m97 staging, 2-bit XOR chunk swizzle.
// V epilogue writes attn-fragment order directly from accumulators:
// Vfrag element offset = (((bh*32+t)*2+wk)*4+nh)*512 + lane*8 + e, where
// e<4 -> key wk*32+quad*4+e (acc[2wk][n]), e>=4 -> key wk*32+16+quad*4+(e-4)
// (acc[2wk+1][n]). Each (wk,nh) block is 1KB, lane-contiguous.
__global__ __launch_bounds__(256, 3)
void gemm_qkv(const bf16_t* __restrict__ qb, const bf16_t* __restrict__ kvb,
              const bf16_t* __restrict__ WqT, const bf16_t* __restrict__ WkvT,
              const float* __restrict__ bq, const float* __restrict__ bkv,
              bf16_t* __restrict__ Qp, bf16_t* __restrict__ Kb,
              bf16_t* __restrict__ Vt) {
    __shared__ __align__(16) char pool[16384];
    bf16_t* sA = (bf16_t*)pool;
    bf16_t* sB = (bf16_t*)(pool + 8192);

    const int tid  = threadIdx.x;
    const int lane = tid & 63, w = tid >> 6;
    const int wr = w >> 1, wc = w & 1;
    const int quad = lane >> 4, l15 = lane & 15;
    const int x3 = l15 & 3;
    const bool isQ = blockIdx.x < 8;
    const bf16_t* A    = isQ ? qb : kvb;
    const bf16_t* BT   = isQ ? WqT : WkvT;
    const float*  bias = isQ ? bq : bkv;
    const int row0 = blockIdx.y * 128;
    const int col0 = (isQ ? blockIdx.x : (blockIdx.x - 8)) * 128;
    const int K = 1024;

    f32x4 acc[4][4];
    const f32x4 fz = {0.f, 0.f, 0.f, 0.f};
#pragma unroll
    for (int m = 0; m < 4; ++m)
#pragma unroll
        for (int n = 0; n < 4; ++n) acc[m][n] = fz;

    for (int kt = 0; kt < K; kt += 32) {
#pragma unroll
        for (int i = 0; i < 2; ++i) {
            int c = i * 256 + tid;
            int r = c >> 2, cr = c & 3;
            int g = cr ^ (r & 3);
            gload16(A + (size_t)(row0 + r) * K + kt + g * 8,
                    (const char*)sA + i * 4096 + w * 1024);
            gload16(BT + (size_t)(col0 + r) * K + kt + g * 8,
                    (const char*)sB + i * 4096 + w * 1024);
        }
        __syncthreads();

        bf16x8 af[4], bfr[4];
#pragma unroll
        for (int m = 0; m < 4; ++m)
            af[m] = *(const bf16x8*)(sA + (wr * 64 + m * 16 + l15) * 32 + (quad ^ x3) * 8);
#pragma unroll
        for (int n = 0; n < 4; ++n)
            bfr[n] = *(const bf16x8*)(sB + (wc * 64 + n * 16 + l15) * 32 + (quad ^ x3) * 8);
#pragma unroll
        for (int m = 0; m < 4; ++m)
#pragma unroll
            for (int n = 0; n < 4; ++n)
                acc[m][n] = MFMA16x32(af[m], bfr[n], acc[m][n]);
        __syncthreads();
    }

    if (!isQ && col0 >= 1024) {
        // pure-V block: write Vfrag directly from accumulators (coalesced
        // 16B/lane stores, 1KB per (wk,nh) block). No LDS transpose.
        const int j0  = col0 - 1024 + wc * 64;   // V column base = head h*64
        const int hh  = j0 >> 6;                 // head index
        const int sk0 = row0 + wr * 64;          // key base (one 64-key tile)
        const int bb  = sk0 >> 11;               // batch
        const int tt  = (sk0 & 2047) >> 6;       // key tile within batch-head
        bf16_t* vdst = Vt + ((((size_t)(bb * 16 + hh) * 32 + tt) * 2) * 4) * 512 +
                       (size_t)lane * 8;
#pragma unroll
        for (int wkh = 0; wkh < 2; ++wkh)
#pragma unroll
            for (int n = 0; n < 4; ++n) {
                float bv = bkv[1024 + j0 + n * 16 + l15];
                bf16x8 v8;
#pragma unroll
                for (int r = 0; r < 4; ++r) {
                    v8[r]     = (bf16_t)(acc[2 * wkh][n][r] + bv);
                    v8[4 + r] = (bf16_t)(acc[2 * wkh + 1][n][r] + bv);
                }
                *(bf16x8*)(vdst + ((size_t)wkh * 4 + n) * 512) = v8;
            }
        return;
    }

#pragma unroll
    for (int m = 0; m < 4; ++m) {
        int rg_base = row0 + wr * 64 + m * 16 + quad * 4;
#pragma unroll
        for (int n = 0; n < 4; ++n) {
            int cg = col0 + wc * 64 + n * 16 + l15;
            float bv = bias[cg];
#pragma unroll
            for (int r = 0; r < 4; ++r) {
                int rg = rg_base + r;
                float v = acc[m][n][r] + bv;
                int bb = rg >> 11, sr = rg & 2047;
                int hh = cg >> 6, hd = cg & 63;
                size_t idx = (((size_t)(bb * 16 + hh) * 2048 + sr) << 6) | hd;
                if (isQ) Qp[idx] = (bf16_t)(v * ATTN_SCALE);
                else     Kb[idx] = (bf16_t)v;
            }
        }
    }
}

// ---------------------------------------------------------------------------
// Oproj GEMM: C = A(MxK) * BT(NxK)^T + bias, fp32 row-major out.
__global__ __launch_bounds__(256, 3)
void gemm_out(const bf16_t* __restrict__ A, const bf16_t* __restrict__ BT,
              const float* __restrict__ bias, float* __restrict__ out,
              int M, int N, int K) {
    __shared__ __align__(16) bf16_t sA[128 * 32];
    __shared__ __align__(16) bf16_t sB[128 * 32];
    const int tid  = threadIdx.x;
    const int lane = tid & 63, w = tid >> 6;
    const int wr = w >> 1, wc = w & 1;
    const int quad = lane >> 4, l15 = lane & 15;
    const int x3 = l15 & 3;
    const int row0 = blockIdx.y * 128, col0 = blockIdx.x * 128;

    f32x4 acc[4][4];
    const f32x4 fz = {0.f, 0.f, 0.f, 0.f};
#pragma unroll
    for (int m = 0; m < 4; ++m)
#pragma unroll
        for (int n = 0; n < 4; ++n) acc[m][n] = fz;

    for (int kt = 0; kt < K; kt += 32) {
#pragma unroll
        for (int i = 0; i < 2; ++i) {
            int c = i * 256 + tid;
            int r = c >> 2, cr = c & 3;
            int g = cr ^ (r & 3);
            gload16(A + (size_t)(row0 + r) * K + kt + g * 8,
                    (const char*)sA + i * 4096 + w * 1024);
            gload16(BT + (size_t)(col0 + r) * K + kt + g * 8,
                    (const char*)sB + i * 4096 + w * 1024);
        }
        __syncthreads();

        bf16x8 af[4], bfr[4];
#pragma unroll
        for (int m = 0; m < 4; ++m)
            af[m] = *(const bf16x8*)(sA + (wr * 64 + m * 16 + l15) * 32 + (quad ^ x3) * 8);
#pragma unroll
        for (int n = 0; n < 4; ++n)
            bfr[n] = *(const bf16x8*)(sB + (wc * 64 + n * 16 + l15) * 32 + (quad ^ x3) * 8);
#pragma unroll
        for (int m = 0; m < 4; ++m)
#pragma unroll
            for (int n = 0; n < 4; ++n)
                acc[m][n] = MFMA16x32(af[m], bfr[n], acc[m][n]);
        __syncthreads();
    }

#pragma unroll
    for (int m = 0; m < 4; ++m) {
        int rg_base = row0 + wr * 64 + m * 16 + quad * 4;
#pragma unroll
        for (int n = 0; n < 4; ++n) {
            int cg = col0 + wc * 64 + n * 16 + l15;
            float bv = bias[cg];
#pragma unroll
            for (int r = 0; r < 4; ++r)
                out[(size_t)(rg_base + r) * N + cg] = acc[m][n][r] + bv;
        }
    }
}

// ---------------------------------------------------------------------------
// Flash attention. 1-D grid of 2048 blocks, bh-major: bh = id&63, qt = id>>6.
// Wave w = (wq = w>>1 q-half, wk = w&1 key-half): 32 q-rows x 32 keys per
// wave, all MFMAs full-rate 16x16x32. In-tile order: QK -> exp -> PV.
// R14 structure (barrier-free, per-wave private K ring, V from Vfrag) with
// the R15 vmcnt-order fix: per tile, vf loads issue FIRST, then K(t+1)
// stages. In-order vmcnt retirement then makes PV's vf wait vmcnt(4)
// (K stages stay in flight) instead of a full drain; the tile-top
// vmcnt(0) waits only on K stages issued a full tile earlier (free).
// sched_barrier(0) after the vf loads pins the issue order.
// Pool 40960B: sQ@0 (8KB, persistent), rings@8192 (4x8KB) -> 4 blocks/CU.
// Epilogue: one barrier to drain all waves (rings overlay redO/redL),
// then redL write, then the 2-phase redO reduction.
// __launch_bounds__(256,4); spill tripwire: WRITE_SIZE ~16.7k.
__global__ __launch_bounds__(256, 4)
void attn_kernel(const bf16_t* __restrict__ Qp, const bf16_t* __restrict__ Kb,
                 const bf16_t* __restrict__ Vt, bf16_t* __restrict__ Ob) {
    __shared__ __align__(16) char pool[40960];
    bf16_t* sQ   = (bf16_t*)pool;
    float*  redO = (float*)pool;               // [4][32][32] (end phase)
    float*  redL = (float*)(pool + 16384);     // [4][32]   (end phase)

    const int tid = threadIdx.x;
    const int lane = tid & 63, w = tid >> 6;
    const int wq = w >> 1, wk = w & 1;
    const int quad = lane >> 4, l15 = lane & 15;
    const int x7 = l15 & 7;
    const int bhid = blockIdx.x & 63;
    const int qt   = blockIdx.x >> 6;
    const int b = bhid >> 4, h = bhid & 15;
    const size_t bh = (size_t)bhid;

    const bf16_t* Qg = Qp + bh * (2048 * 64) + (size_t)qt * (64 * 64);
    const bf16_t* Kg = Kb + bh * (2048 * 64);
    // Vfrag: element = bh*131072 + t*4096 + wk*2048 + nh*512 + lane*8 + e
    const bf16_t* vtile = Vt + bh * 131072 + (size_t)wk * 2048 + (size_t)lane * 8;

    // Q staging map (block-cooperative)
    const int srow = tid >> 3;
    const int sg   = (tid & 7) ^ (srow & 7);

    // K private-ring staging map: wave stages rows wk*32 + j*8 + (lane>>3),
    // slot lane&7 <- global chunk (lane&7)^(lane>>3)
    const bf16_t* Kw = Kg + wk * 2048;           // our 32-key half, tile 0
    const int krl = lane >> 3;
    const size_t klo = (size_t)krl * 64 + (size_t)(((lane & 7) ^ krl)) * 8;
    char* kring = pool + 8192 + w * 8192;

    // stage Q (cooperative) + K(0) (private)
#pragma unroll
    for (int hh = 0; hh < 2; ++hh) {
        int row = hh * 32 + srow;
        gload16(Qg + (size_t)row * 64 + sg * 8, pool + hh * 4096 + w * 1024);
    }
#pragma unroll
    for (int j = 0; j < 4; ++j)
        gload16(Kw + (size_t)j * 512 + klo, kring + j * 1024);
    __syncthreads();   // sQ fully staged (also drains our K(0) gload16s)

    // Q B-frags: our 32 q-rows, both hd halves (sQ persists all loop)
    bf16x8 qf[2][2];
#pragma unroll
    for (int qb = 0; qb < 2; ++qb)
#pragma unroll
        for (int hh = 0; hh < 2; ++hh)
            qf[qb][hh] = *(const bf16x8*)(sQ + (wq * 32 + qb * 16 + l15) * 64 +
                                          ((hh * 4 + quad) ^ x7) * 8);

    const f32x4 fz = {0.f, 0.f, 0.f, 0.f};
    bf16x8 ones8;
#pragma unroll
    for (int i = 0; i < 8; ++i) ones8[i] = (bf16_t)1.f;

    f32x4 o_[2][4];   // [qb][nh]: O[wq*32+qb*16+quad*4+r][nh*16+l15], partial over our keys
    f32x4 lacc[2];    // [qb]: row-sum partials
#pragma unroll
    for (int qb = 0; qb < 2; ++qb) {
        lacc[qb] = fz;
#pragma unroll
        for (int nh = 0; nh < 4; ++nh) o_[qb][nh] = fz;
    }

    for (int t = 0; t < 32; ++t) {
        // K(t) ring ready: only its 4 stages can be outstanding here
        asm volatile("s_waitcnt vmcnt(0)" ::: "memory");

        // V(t) FIRST (coalesced 16B/lane): with in-order vmcnt retirement,
        // PV's wait for vf becomes vmcnt(4), leaving K(t+1) stages in flight
        bf16x8 vf[4];
#pragma unroll
        for (int nh = 0; nh < 4; ++nh)
            vf[nh] = *(const bf16x8*)(vtile + (size_t)t * 4096 + nh * 512);
        __builtin_amdgcn_sched_barrier(0);   // pin: vf issued before K stages

        // stage K(t+1) into the other ring half (private, no barrier)
        if (t < 31) {
            const bf16_t* Kt = Kw + (size_t)(t + 1) * 4096;
            char* kb_ = kring + (((t + 1) & 1) << 12);
#pragma unroll
            for (int j = 0; j < 4; ++j)
                gload16(Kt + (size_t)j * 512 + klo, kb_ + j * 1024);
        }

        const bf16_t* k0 = (const bf16_t*)(kring + ((t & 1) << 12));
        bf16x8 kf0[2], kf1[2];
#pragma unroll
        for (int kg = 0; kg < 2; ++kg) {
            const bf16_t* krow = k0 + (kg * 16 + l15) * 64;
            kf0[kg] = *(const bf16x8*)(krow + (quad ^ x7) * 8);
            kf1[kg] = *(const bf16x8*)(krow + ((quad + 4) ^ x7) * 8);
        }

        // QK: S^T[key=wk*32+kg*16+quad*4+r][qrow=wq*32+qb*16+l15]
        f32x4 s_[2][2];
#pragma unroll
        for (int kg = 0; kg < 2; ++kg)
#pragma unroll
            for (int qb = 0; qb < 2; ++qb) {
                s_[kg][qb] = MFMA16x32(kf0[kg], qf[qb][0], fz);
                s_[kg][qb] = MFMA16x32(kf1[kg], qf[qb][1], s_[kg][qb]);
            }

        // p = exp2(s), packed K=32 A-frags (e<4: kg0, e>=4: kg1);
        // row sums via K=32 MFMA against ones
        bf16x8 pf8[2];
#pragma unroll
        for (int qb = 0; qb < 2; ++qb) {
#pragma unroll
            for (int kg = 0; kg < 2; ++kg)
#pragma unroll
                for (int r = 0; r < 4; ++r)
                    pf8[qb][kg * 4 + r] = (bf16_t)fast_exp2(s_[kg][qb][r]);
            lacc[qb] = MFMA16x32(pf8[qb], ones8, lacc[qb]);
        }

        // PV: vf virtual k-order matches pf8 (Vfrag layout)
#pragma unroll
        for (int nh = 0; nh < 4; ++nh)
#pragma unroll
            for (int qb = 0; qb < 2; ++qb)
                o_[qb][nh] = MFMA16x32(pf8[qb], vf[nh], o_[qb][nh]);
        // no __syncthreads: waves drift freely
    }

    // ---- epilogue: drain all waves, then 2-way cross-wave (wk) reduction ----
    __syncthreads();   // all waves done with their K rings (redO/redL overlay)

    if (l15 == 0) {
#pragma unroll
        for (int qb = 0; qb < 2; ++qb)
#pragma unroll
            for (int r = 0; r < 4; ++r)
                redL[w * 32 + qb * 16 + quad * 4 + r] = lacc[qb][r];
    }

    const int cq  = tid >> 2;           // consumer q-row 0..63
    const int cwq = cq >> 5, cql = cq & 31;
    const int chb = (tid & 3) * 8;      // consumer hd base within 32-phase
    const size_t orow = (size_t)b * 2048 + (size_t)qt * 64 + cq;

#pragma unroll
    for (int ph = 0; ph < 2; ++ph) {
        __syncthreads();  // prior phase consumed; redL visible (ph=0)
#pragma unroll
        for (int qb = 0; qb < 2; ++qb)
#pragma unroll
            for (int nj = 0; nj < 2; ++nj) {
                int nh = ph * 2 + nj;
#pragma unroll
                for (int r = 0; r < 4; ++r)
                    redO[w * 1024 + (qb * 16 + quad * 4 + r) * 32 + nj * 16 + l15] =
                        o_[qb][nh][r];
            }
        __syncthreads();  // partials visible

        float lt = redL[cwq * 64 + cql] + redL[cwq * 64 + 32 + cql];
        float linv = 1.f / lt;
        float4 a0 = {0, 0, 0, 0}, a1 = {0, 0, 0, 0};
#pragma unroll
        for (int wk2 = 0; wk2 < 2; ++wk2) {
            const float4* p = (const float4*)(redO + (cwq * 2 + wk2) * 1024 + cql * 32 + chb);
            float4 x = p[0], y = p[1];
            a0.x += x.x; a0.y += x.y; a0.z += x.z; a0.w += x.w;
            a1.x += y.x; a1.y += y.y; a1.z += y.z; a1.w += y.w;
        }
        bf16x8 ov;
        ov[0] = (bf16_t)(a0.x * linv); ov[1] = (bf16_t)(a0.y * linv);
        ov[2] = (bf16_t)(a0.z * linv); ov[3] = (bf16_t)(a0.w * linv);
        ov[4] = (bf16_t)(a1.x * linv); ov[5] = (bf16_t)(a1.y * linv);
        ov[6] = (bf16_t)(a1.z * linv); ov[7] = (bf16_t)(a1.w * linv);
        *(bf16x8*)(Ob + orow * 1024 + h * 64 + ph * 32 + chb) = ov;
    }
}

// ---------------------------------------------------------------------------
extern "C" void kernel_launch(void* const* d_in, const int* in_sizes, int n_in,
                              void* d_out, int out_size, void* d_ws, size_t ws_size,
                              hipStream_t stream) {
    const float* query     = (const float*)d_in[0];
    const float* key_value = (const float*)d_in[1];
    const float* Wq  = (const float*)d_in[2];
    const float* bq  = (const float*)d_in[3];
    const float* Wkv = (const float*)d_in[4];
    const float* bkv = (const float*)d_in[5];
    const float* Wo  = (const float*)d_in[6];
    const float* bo  = (const float*)d_in[7];
    float* out = (float*)d_out;

    char* ws = (char*)d_ws;
    const size_t MB = 1024 * 1024;
    bf16_t* WqT  = (bf16_t*)(ws + 0 * MB);
    bf16_t* WkvT = (bf16_t*)(ws + 2 * MB);
    bf16_t* WoT  = (bf16_t*)(ws + 6 * MB);
    bf16_t* qb   = (bf16_t*)(ws + 8 * MB);
    bf16_t* kvb  = (bf16_t*)(ws + 24 * MB);
    bf16_t* Qp   = (bf16_t*)(ws + 40 * MB);
    bf16_t* Kb   = (bf16_t*)(ws + 56 * MB);
    bf16_t* Vt   = (bf16_t*)(ws + 72 * MB);
    bf16_t* Ob   = (bf16_t*)(ws + 88 * MB);

    prep_kernel<<<9728, 256, 0, stream>>>(query, key_value, Wq, Wkv, Wo,
                                          qb, kvb, WqT, WkvT, WoT);
    gemm_qkv<<<dim3(24, 64), 256, 0, stream>>>(qb, kvb, WqT, WkvT, bq, bkv,
                                               Qp, Kb, Vt);
    attn_kernel<<<2048, 256, 0, stream>>>(Qp, Kb, Vt, Ob);
    gemm_out<<<dim3(8, 64), 256, 0, stream>>>(Ob, WoT, bo, out, 8192, 1024, 1024);
}